// Round 10
// baseline (78.019 us; speedup 1.0000x reference)
//
#include <hip/hip_runtime.h>

// ShiftGraph: B=8, C=16, H=W=256, d=5 (r=2), 24 shifts.
// Output (flat float32): edges (B, E, 2) then ws (B, E), E = 1557540.
// R9: 4 pixels/thread; per (channel,row) three aligned float4 loads cover the
// 12-col window -> all 5 dj variants for 4 pixels. Load instrs 400->60 /pixel.
// b = blockIdx.x & 7 pins each batch's 4 MB x-slice to one XCD L2.

#define HH 256
#define WW 256
#define CC 16
#define BB 8
#define HW (HH * WW)
#define EE 1557540

__global__ __launch_bounds__(256) void shiftgraph_kernel(
    const float* __restrict__ x, float* __restrict__ out) {
    const int wg  = blockIdx.x;      // 0..511
    const int b   = wg & 7;          // batch -> XCD
    const int hg  = wg >> 3;         // row-group 0..63
    const int tid = threadIdx.x;
    const int q   = tid & 63;        // pixel-quad index; w = 4q..4q+3
    const int rr  = tid >> 6;        // row within group
    const int h   = hg * 4 + rr;
    const int wbase = q * 4;

    const float* __restrict__ xb = x + (size_t)b * (CC * HW);

    float acc[24][4];
#pragma unroll
    for (int s = 0; s < 24; ++s)
#pragma unroll
        for (int p = 0; p < 4; ++p) acc[s][p] = 0.0f;

    // three aligned quads covering cols [4q-4 .. 4q+7], clamped at edges
    // (clamped values feed only per-shift-invalid lanes, never stored)
    const int cA = (q == 0)  ? 0   : (wbase - 4);
    const int cB = wbase;
    const int cC = (q == 63) ? 252 : (wbase + 4);

    for (int c = 0; c < CC; ++c) {
        const float* __restrict__ xc = xb + c * HW;
        const float4 ctr = *reinterpret_cast<const float4*>(xc + h * WW + cB);
        const float cw[4] = {ctr.x, ctr.y, ctr.z, ctr.w};
#pragma unroll
        for (int i = 0; i < 5; ++i) {
            const int di = i - 2;
            const int h2 = h + di;
            if (h2 < 0 || h2 >= HH) continue;
            const float* __restrict__ row = xc + h2 * WW;
            const float4 qa = *reinterpret_cast<const float4*>(row + cA);
            const float4 qb = *reinterpret_cast<const float4*>(row + cB);
            const float4 qc = *reinterpret_cast<const float4*>(row + cC);
            const float wnd[12] = {qa.x, qa.y, qa.z, qa.w,
                                   qb.x, qb.y, qb.z, qb.w,
                                   qc.x, qc.y, qc.z, qc.w};
#pragma unroll
            for (int j = 0; j < 5; ++j) {
                if (i == 2 && j == 2) continue;
                const int dj = j - 2;
                const int s = i * 5 + j - (i * 5 + j > 12 ? 1 : 0);
#pragma unroll
                for (int p = 0; p < 4; ++p) {
                    const float d = wnd[4 + p + dj] - cw[p];
                    acc[s][p] = fmaf(d, d, acc[s][p]);
                }
            }
        }
    }

    const int pos = h * WW + wbase;                         // pixel p adds +p
    float* __restrict__ edges = out;                        // (B, E, 2)
    float* __restrict__ wsp   = out + (size_t)BB * EE * 2;  // (B, E)

    int off = 0;
#pragma unroll
    for (int i = 0; i < 5; ++i) {
#pragma unroll
        for (int j = 0; j < 5; ++j) {
            if (i == 2 && j == 2) continue;
            const int di = i - 2, dj = j - 2;
            const int adi = di < 0 ? -di : di;
            const int adj = dj < 0 ? -dj : dj;
            const int cnt = (HH - adi) * (WW - adj);
            const int s = i * 5 + j - (i * 5 + j > 12 ? 1 : 0);
            const int h2 = h + di;
            if (h2 >= 0 && h2 < HH) {
                const int h0 = di < 0 ? -di : 0;
                const int w0 = dj < 0 ? -dj : 0;
                const int cww = WW - adj;
                const float scale = sqrtf((float)(di * di + dj * dj));
                const int posv = di * WW + dj;
                const size_t beb = (size_t)b * EE + off + (h - h0) * cww + (wbase - w0);
                if (q > 0 && q < 63) {
#pragma unroll
                    for (int p = 0; p < 4; ++p) {
                        *reinterpret_cast<float2*>(edges + (beb + p) * 2) =
                            make_float2((float)(pos + p), (float)(pos + p + posv));
                        wsp[beb + p] = -acc[s][p] * scale;
                    }
                } else {
#pragma unroll
                    for (int p = 0; p < 4; ++p) {
                        const int w2 = wbase + p + dj;
                        if (w2 >= 0 && w2 < WW) {
                            *reinterpret_cast<float2*>(edges + (beb + p) * 2) =
                                make_float2((float)(pos + p), (float)(pos + p + posv));
                            wsp[beb + p] = -acc[s][p] * scale;
                        }
                    }
                }
            }
            off += cnt;
        }
    }
}

extern "C" void kernel_launch(void* const* d_in, const int* in_sizes, int n_in,
                              void* d_out, int out_size, void* d_ws, size_t ws_size,
                              hipStream_t stream) {
    const float* x = (const float*)d_in[0];
    float* out = (float*)d_out;
    dim3 block(256);          // 4 rows x 64 quads
    dim3 grid(BB * 64);       // one block per (batch, 4-row group)
    shiftgraph_kernel<<<grid, block, 0, stream>>>(x, out);
}

// Round 11
// 41.968 us; speedup vs baseline: 1.8590x; 1.8590x over previous
//
#include <hip/hip_runtime.h>

// ShiftGraph: B=8, C=16, H=W=256, d=5 (r=2), 24 shifts.
// Output (flat float32): edges (B, E, 2) then ws (B, E), E = 1557540.
// R11: R9 structure (1 px/thread, 2048 blocks, 32 waves/CU) + PAIR SYMMETRY:
// ws[(di,dj) @ p] == ws[(-di,-dj) @ p+v]  -> compute 12 forward shifts, write
// both entries. Halves loads (400->208) & FMAs at unchanged occupancy.
// Nontemporal stores keep x resident in L2. b = bid&7 pins batch to one XCD.

#define HH 256
#define WW 256
#define CC 16
#define BB 8
#define HW (HH * WW)
#define EE 1557540

__global__ __launch_bounds__(256) void shiftgraph_kernel(
    const float* __restrict__ x, float* __restrict__ out) {
    const int bid = blockIdx.x;
    const int b = bid & 7;          // batch -> XCD
    const int h = bid >> 3;         // row
    const int w = threadIdx.x;      // col

    const float* __restrict__ xb = x + (size_t)b * (CC * HW);

    // center pixel, all channels
    float c0[CC];
#pragma unroll
    for (int c = 0; c < CC; ++c)
        c0[c] = xb[c * HW + h * WW + w];

    const int pos = h * WW + w;
    float* __restrict__ edges = out;                        // (B, E, 2)
    float* __restrict__ wsp   = out + (size_t)BB * EE * 2;  // (B, E)
    const size_t bE = (size_t)b * EE;

    // forward shifts S+: (i==2, j>2) or i>2   (di = i-2 >= 0)
#pragma unroll
    for (int i = 2; i < 5; ++i) {
#pragma unroll
        for (int j = (i == 2 ? 3 : 0); j < 5; ++j) {
            const int di = i - 2, dj = j - 2;
            const int h2 = h + di;
            if (h2 >= HH) continue;              // uniform across block
            const int w2 = w + dj;
            if (w2 < 0 || w2 >= WW) continue;    // <=2 edge lanes diverge

            float sum = 0.0f;
#pragma unroll
            for (int c = 0; c < CC; ++c) {
                const float d = xb[c * HW + h2 * WW + w2] - c0[c];
                sum = fmaf(d, d, sum);
            }
            const float scale = sqrtf((float)(di * di + dj * dj));
            const float wsv = -sum * scale;

            // compile-time prefix offsets for (i,j) and mirror (4-i,4-j)
            int offF = 0, offM = 0;
#pragma unroll
            for (int m = 0; m < 25; ++m) {
                const int mi = m / 5, mj = m % 5;
                if (mi == 2 && mj == 2) continue;
                const int cm = (HH - (mi < 2 ? 2 - mi : mi - 2)) *
                               (WW - (mj < 2 ? 2 - mj : mj - 2));
                if (m < i * 5 + j) offF += cm;
                if (m < (4 - i) * 5 + (4 - j)) offM += cm;
            }
            const int cww = WW - (dj < 0 ? -dj : dj);
            const int e1 = offF + h * cww + (w - (dj < 0 ? -dj : 0));
            const int e2 = offM + h * cww + (w + (dj < 0 ? dj : 0));
            const int posv = di * WW + dj;

            union { float f[2]; unsigned long long u; } evF, evM;
            evF.f[0] = (float)pos;          evF.f[1] = (float)(pos + posv);
            evM.f[0] = (float)(pos + posv); evM.f[1] = (float)pos;

            __builtin_nontemporal_store(
                evF.u, reinterpret_cast<unsigned long long*>(edges + (bE + e1) * 2));
            __builtin_nontemporal_store(
                evM.u, reinterpret_cast<unsigned long long*>(edges + (bE + e2) * 2));
            __builtin_nontemporal_store(wsv, wsp + bE + e1);
            __builtin_nontemporal_store(wsv, wsp + bE + e2);
        }
    }
}

extern "C" void kernel_launch(void* const* d_in, const int* in_sizes, int n_in,
                              void* d_out, int out_size, void* d_ws, size_t ws_size,
                              hipStream_t stream) {
    const float* x = (const float*)d_in[0];
    float* out = (float*)d_out;
    dim3 block(WW);            // one thread per column
    dim3 grid(HH * BB);        // one block per (row, batch)
    shiftgraph_kernel<<<grid, block, 0, stream>>>(x, out);
}